// Round 1
// baseline (2499.285 us; speedup 1.0000x reference)
//
#include <hip/hip_runtime.h>
#include <hip/hip_bf16.h>

using uint32 = unsigned int;
using u16 = unsigned short;

// ---------- bf16 helpers ----------
__device__ __forceinline__ float bf2f(u16 u) {
  union { uint32 i; float f; } c; c.i = ((uint32)u) << 16; return c.f;
}
__device__ __forceinline__ u16 f2bf(float f) {
  union { float f; uint32 i; } c; c.f = f;
  uint32 u = c.i;
  u += 0x7fffu + ((u >> 16) & 1u);   // RNE
  return (u16)(u >> 16);
}
__device__ __forceinline__ uint32 pack2(float a, float b) {
  return (uint32)f2bf(a) | ((uint32)f2bf(b) << 16);
}
__device__ __forceinline__ void up2(uint32 u, float& a, float& b) {
  union { uint32 i; float f; } x, y;
  x.i = u << 16; y.i = u & 0xffff0000u;
  a = x.f; b = y.f;
}

// Sizes
// B=16, C=64, W=256, H=128, H'=122, KW=7
// k/q layout: [b][co][w][h'] contiguous == (B,256,7808) attention rows
// v = x raw: (B,256,8192); x1 same layout (== NCHW image)

// ---------------------------------------------------------------
// Kernel 1: K and Q convs (fp32 in, bf16 out), block = one (b,w)
// ---------------------------------------------------------------
__global__ __launch_bounds__(256) void conv_kq_kernel(
    const float* __restrict__ x,
    const float* __restrict__ wK, const float* __restrict__ bK,
    const float* __restrict__ wQ, const float* __restrict__ bQ,
    u16* __restrict__ qbuf, u16* __restrict__ kbuf)
{
  __shared__ float lx[64 * 144 + 8];  // skewed x rows: ci*144 + h + 4*(h>>5)
  __shared__ float lw[64 * 58];       // weights: co*58 + conv*29 + cl*7 + kw
  const int bid = blockIdx.x;
  const int b = bid >> 8, w = bid & 255;
  const int t = threadIdx.x;

  const float* xb = x + (size_t)b * 2097152 + (size_t)w * 128;
  #pragma unroll
  for (int j = 0; j < 8; ++j) {
    int f4 = t + j * 256;           // 0..2047 float4s
    int ci = f4 >> 5, h4 = f4 & 31;
    float4 v = *reinterpret_cast<const float4*>(xb + (size_t)ci * 32768 + h4 * 4);
    int h = h4 * 4;
    *reinterpret_cast<float4*>(&lx[ci * 144 + h + 4 * (h >> 5)]) = v;
  }

  const int co = t >> 2, qd = t & 3;
  float accK[32], accQ[32];
  const float bk = bK[co], bq = bQ[co];
  #pragma unroll
  for (int o = 0; o < 32; ++o) { accK[o] = bk; accQ[o] = bq; }

  for (int ci0 = 0; ci0 < 64; ci0 += 4) {
    __syncthreads();
    // stage both convs' weight slice: 2*64*4*7 = 3584 floats
    for (int idx = t; idx < 3584; idx += 256) {
      int conv = idx / 1792;
      int r = idx - conv * 1792;
      int cos = r / 28;
      int r2 = r - cos * 28;        // cl*7+kw
      const float* wsel = conv ? wQ : wK;
      lw[cos * 58 + conv * 29 + r2] = wsel[cos * 448 + ci0 * 7 + r2];
    }
    __syncthreads();
    #pragma unroll
    for (int cl = 0; cl < 4; ++cl) {
      int ci = ci0 + cl;
      float xv[38];
      const float* xr = &lx[ci * 144 + 36 * qd];
      #pragma unroll
      for (int u = 0; u < 38; ++u) xv[u] = xr[u + 4 * (u >> 5)];
      float wk7[7], wq7[7];
      const float* wr = &lw[co * 58 + cl * 7];
      #pragma unroll
      for (int k = 0; k < 7; ++k) { wk7[k] = wr[k]; wq7[k] = wr[29 + k]; }
      #pragma unroll
      for (int o = 0; o < 32; ++o) {
        #pragma unroll
        for (int k = 0; k < 7; ++k) {
          accK[o] = fmaf(xv[o + k], wk7[k], accK[o]);
          accQ[o] = fmaf(xv[o + k], wq7[k], accQ[o]);
        }
      }
    }
  }

  const int h0 = qd * 32;
  const int nout = (qd == 3) ? 26 : 32;
  size_t rowoff = ((size_t)(b * 64 + co) * 256 + w) * 122 + h0;
  u16* ko = kbuf + rowoff;
  u16* qo = qbuf + rowoff;
  for (int o = 0; o < nout; o += 2) {
    *reinterpret_cast<uint32*>(ko + o) = pack2(accK[o], accK[o + 1]);
    *reinterpret_cast<uint32*>(qo + o) = pack2(accQ[o], accQ[o + 1]);
  }
}

// ---------------------------------------------------------------
// Kernel 2a: scores (Q.K^T / sqrt(d)) + masked softmax -> pbuf fp32
// block = (b, 16-row tile), 512 threads; thread = (row, 4 cols)
// ---------------------------------------------------------------
__device__ __forceinline__ float dotk(const float* qf, uint4 kv, float acc) {
  float a, b;
  up2(kv.x, a, b); acc = fmaf(qf[0], a, acc); acc = fmaf(qf[1], b, acc);
  up2(kv.y, a, b); acc = fmaf(qf[2], a, acc); acc = fmaf(qf[3], b, acc);
  up2(kv.z, a, b); acc = fmaf(qf[4], a, acc); acc = fmaf(qf[5], b, acc);
  up2(kv.w, a, b); acc = fmaf(qf[6], a, acc); acc = fmaf(qf[7], b, acc);
  return acc;
}

__global__ __launch_bounds__(512) void scores_softmax_kernel(
    const u16* __restrict__ qbuf, const u16* __restrict__ kbuf,
    float* __restrict__ pbuf)
{
  const int bid = blockIdx.x;          // b*16 + it
  const int b = bid >> 4, it = bid & 15;
  const int t = threadIdx.x;
  const int il = t >> 5, jg = t & 31;
  const int i = it * 16 + il;
  const int jbase = (it < 8) ? 128 : 0;

  const u16* qr = qbuf + (size_t)(b * 256 + i) * 7808;
  const u16* k0p = kbuf + (size_t)(b * 256 + jbase + jg * 4) * 7808;
  const u16* k1p = k0p + 7808;
  const u16* k2p = k0p + 2 * 7808;
  const u16* k3p = k0p + 3 * 7808;

  float d0 = 0.f, d1 = 0.f, d2 = 0.f, d3 = 0.f;
  for (int c = 0; c < 976; ++c) {      // 7808/8 exact
    uint4 qv = *reinterpret_cast<const uint4*>(qr + c * 8);
    float qf[8];
    up2(qv.x, qf[0], qf[1]); up2(qv.y, qf[2], qf[3]);
    up2(qv.z, qf[4], qf[5]); up2(qv.w, qf[6], qf[7]);
    uint4 k0 = *reinterpret_cast<const uint4*>(k0p + c * 8);
    uint4 k1 = *reinterpret_cast<const uint4*>(k1p + c * 8);
    uint4 k2 = *reinterpret_cast<const uint4*>(k2p + c * 8);
    uint4 k3 = *reinterpret_cast<const uint4*>(k3p + c * 8);
    d0 = dotk(qf, k0, d0); d1 = dotk(qf, k1, d1);
    d2 = dotk(qf, k2, d2); d3 = dotk(qf, k3, d3);
  }
  const float scale = 0.011316967f;    // 1/sqrt(7808)
  d0 *= scale; d1 *= scale; d2 *= scale; d3 *= scale;

  // row reduce across the 32 lanes holding this row
  float m = fmaxf(fmaxf(d0, d1), fmaxf(d2, d3));
  #pragma unroll
  for (int off = 16; off >= 1; off >>= 1) m = fmaxf(m, __shfl_xor(m, off));
  float e0 = __expf(d0 - m), e1 = __expf(d1 - m);
  float e2 = __expf(d2 - m), e3 = __expf(d3 - m);
  float s = e0 + e1 + e2 + e3;
  #pragma unroll
  for (int off = 16; off >= 1; off >>= 1) s += __shfl_xor(s, off);
  float inv = 1.0f / s;

  float4 p4 = make_float4(e0 * inv, e1 * inv, e2 * inv, e3 * inv);
  *reinterpret_cast<float4*>(pbuf + (size_t)(b * 256 + i) * 128 + jg * 4) = p4;
}

// ---------------------------------------------------------------
// Kernel 2b: x1 = P * V (V = x raw rows), bf16 out
// grid = b(16) x it(16) x ec(16); thread = 4 rows x 8 cols
// ---------------------------------------------------------------
__global__ __launch_bounds__(256) void pv_kernel(
    const float* __restrict__ pbuf, const float* __restrict__ x,
    u16* __restrict__ x1buf)
{
  __shared__ float lp[16 * 129];
  const int bid = blockIdx.x;
  const int b = bid >> 8, r = bid & 255;
  const int it = r >> 4, ec = r & 15;
  const int t = threadIdx.x;

  for (int idx = t; idx < 2048; idx += 256) {
    int il = idx >> 7, jj = idx & 127;
    lp[il * 129 + jj] = pbuf[(size_t)(b * 256 + it * 16 + il) * 128 + jj];
  }
  __syncthreads();

  const int ig = t >> 6, eg = t & 63;
  const int jbase = (it < 8) ? 128 : 0;
  const float* vb = x + (size_t)b * 2097152 + (size_t)jbase * 8192 + ec * 512 + eg * 8;

  float acc[4][8];
  #pragma unroll
  for (int rr = 0; rr < 4; ++rr)
    #pragma unroll
    for (int e = 0; e < 8; ++e) acc[rr][e] = 0.f;

  for (int j = 0; j < 128; ++j) {
    const float* vr = vb + (size_t)j * 8192;
    float4 va = *reinterpret_cast<const float4*>(vr);
    float4 vb4 = *reinterpret_cast<const float4*>(vr + 4);
    #pragma unroll
    for (int rr = 0; rr < 4; ++rr) {
      float pj = lp[(ig * 4 + rr) * 129 + j];
      acc[rr][0] = fmaf(pj, va.x, acc[rr][0]);
      acc[rr][1] = fmaf(pj, va.y, acc[rr][1]);
      acc[rr][2] = fmaf(pj, va.z, acc[rr][2]);
      acc[rr][3] = fmaf(pj, va.w, acc[rr][3]);
      acc[rr][4] = fmaf(pj, vb4.x, acc[rr][4]);
      acc[rr][5] = fmaf(pj, vb4.y, acc[rr][5]);
      acc[rr][6] = fmaf(pj, vb4.z, acc[rr][6]);
      acc[rr][7] = fmaf(pj, vb4.w, acc[rr][7]);
    }
  }
  #pragma unroll
  for (int rr = 0; rr < 4; ++rr) {
    int i = it * 16 + ig * 4 + rr;
    u16* xo = x1buf + (size_t)(b * 256 + i) * 8192 + ec * 512 + eg * 8;
    uint4 st;
    st.x = pack2(acc[rr][0], acc[rr][1]);
    st.y = pack2(acc[rr][2], acc[rr][3]);
    st.z = pack2(acc[rr][4], acc[rr][5]);
    st.w = pack2(acc[rr][6], acc[rr][7]);
    *reinterpret_cast<uint4*>(xo) = st;
  }
}

// ---------------------------------------------------------------
// Kernel 3: y = LeakyReLU(conv(x1 + x, wV) + bV), fp32 out
// ---------------------------------------------------------------
__global__ __launch_bounds__(256) void conv_out_kernel(
    const float* __restrict__ x, const u16* __restrict__ x1buf,
    const float* __restrict__ wV, const float* __restrict__ bV,
    float* __restrict__ out)
{
  __shared__ float lx[64 * 144 + 8];
  __shared__ float lw[64 * 57];
  const int bid = blockIdx.x;
  const int b = bid >> 8, w = bid & 255;
  const int t = threadIdx.x;

  const float* xb = x + (size_t)b * 2097152 + (size_t)w * 128;
  const u16* x1b = x1buf + (size_t)b * 2097152 + (size_t)w * 128;
  #pragma unroll
  for (int j = 0; j < 8; ++j) {
    int f4 = t + j * 256;
    int ci = f4 >> 5, h4 = f4 & 31;
    float4 v = *reinterpret_cast<const float4*>(xb + (size_t)ci * 32768 + h4 * 4);
    ushort4 u = *reinterpret_cast<const ushort4*>(x1b + (size_t)ci * 32768 + h4 * 4);
    v.x += bf2f(u.x); v.y += bf2f(u.y); v.z += bf2f(u.z); v.w += bf2f(u.w);
    int h = h4 * 4;
    *reinterpret_cast<float4*>(&lx[ci * 144 + h + 4 * (h >> 5)]) = v;
  }

  const int co = t >> 2, qd = t & 3;
  float acc[32];
  const float bv = bV[co];
  #pragma unroll
  for (int o = 0; o < 32; ++o) acc[o] = bv;

  for (int ci0 = 0; ci0 < 64; ci0 += 8) {
    __syncthreads();
    for (int idx = t; idx < 3584; idx += 256) {   // 64*8*7
      int cos = idx / 56;
      int r2 = idx - cos * 56;
      lw[cos * 57 + r2] = wV[cos * 448 + ci0 * 7 + r2];
    }
    __syncthreads();
    #pragma unroll
    for (int cl = 0; cl < 8; ++cl) {
      int ci = ci0 + cl;
      float xv[38];
      const float* xr = &lx[ci * 144 + 36 * qd];
      #pragma unroll
      for (int u = 0; u < 38; ++u) xv[u] = xr[u + 4 * (u >> 5)];
      float wv7[7];
      const float* wr = &lw[co * 57 + cl * 7];
      #pragma unroll
      for (int k = 0; k < 7; ++k) wv7[k] = wr[k];
      #pragma unroll
      for (int o = 0; o < 32; ++o) {
        #pragma unroll
        for (int k = 0; k < 7; ++k) acc[o] = fmaf(xv[o + k], wv7[k], acc[o]);
      }
    }
  }

  const int h0 = qd * 32;
  const int nout = (qd == 3) ? 26 : 32;
  float* orow = out + ((size_t)(b * 64 + co) * 256 + w) * 122 + h0;
  for (int o = 0; o < nout; o += 2) {
    float y0 = acc[o];     y0 = (y0 >= 0.f) ? y0 : 0.2f * y0;
    float y1 = acc[o + 1]; y1 = (y1 >= 0.f) ? y1 : 0.2f * y1;
    float2 st; st.x = y0; st.y = y1;
    *reinterpret_cast<float2*>(orow + o) = st;
  }
}

// ---------------------------------------------------------------
extern "C" void kernel_launch(void* const* d_in, const int* in_sizes, int n_in,
                              void* d_out, int out_size, void* d_ws, size_t ws_size,
                              hipStream_t stream) {
  const float* x  = (const float*)d_in[0];
  const float* wK = (const float*)d_in[1];
  const float* bK = (const float*)d_in[2];
  const float* wQ = (const float*)d_in[3];
  const float* bQ = (const float*)d_in[4];
  const float* wV = (const float*)d_in[5];
  const float* bV = (const float*)d_in[6];
  float* out = (float*)d_out;

  // workspace layout (needs ~188 MiB):
  // qbuf bf16 [16][64][256][122]  : 63,963,136 B
  // kbuf bf16 same                : 63,963,136 B
  // pbuf fp32 [16][256][128]      :  2,097,152 B
  // x1   bf16 [16][256][8192]     : 67,108,864 B
  char* ws = (char*)d_ws;
  u16* qbuf = (u16*)ws;
  u16* kbuf = qbuf + 31981568;
  float* pbuf = (float*)(ws + 127926272);
  u16* x1buf = (u16*)(ws + 130023424);

  conv_kq_kernel<<<dim3(16 * 256), dim3(256), 0, stream>>>(x, wK, bK, wQ, bQ, qbuf, kbuf);
  scores_softmax_kernel<<<dim3(16 * 16), dim3(512), 0, stream>>>(qbuf, kbuf, pbuf);
  pv_kernel<<<dim3(16 * 16 * 16), dim3(256), 0, stream>>>(pbuf, x, x1buf);
  conv_out_kernel<<<dim3(16 * 256), dim3(256), 0, stream>>>(x, x1buf, wV, bV, out);
}

// Round 2
// 1245.427 us; speedup vs baseline: 2.0068x; 2.0068x over previous
//
#include <hip/hip_runtime.h>
#include <hip/hip_bf16.h>

using uint32 = unsigned int;
using u16 = unsigned short;
using short8 = __attribute__((ext_vector_type(8))) short;
using f32x4  = __attribute__((ext_vector_type(4))) float;

// ---------- bf16 helpers ----------
__device__ __forceinline__ float bf2f(u16 u) {
  union { uint32 i; float f; } c; c.i = ((uint32)u) << 16; return c.f;
}
__device__ __forceinline__ u16 f2bf(float f) {
  union { float f; uint32 i; } c; c.f = f;
  uint32 u = c.i;
  u += 0x7fffu + ((u >> 16) & 1u);   // RNE
  return (u16)(u >> 16);
}
__device__ __forceinline__ uint32 pack2(float a, float b) {
  return (uint32)f2bf(a) | ((uint32)f2bf(b) << 16);
}
__device__ __forceinline__ void up2(uint32 u, float& a, float& b) {
  union { uint32 i; float f; } x, y;
  x.i = u << 16; y.i = u & 0xffff0000u;
  a = x.f; b = y.f;
}

// Sizes: B=16, C=64, W=256, H=128, H'=122, KW=7
// k/q layout: [b][co][w][h'] contiguous == (B,256,7808) attention rows
// v = x raw: (B,256,8192); z = x + P*V in same raw layout (== NCHW image)

// ---------------------------------------------------------------
// Kernel 0: prep weights -> bf16 [kw][co][ci]
// ---------------------------------------------------------------
__global__ __launch_bounds__(256) void prep_weights(
    const float* __restrict__ wK, const float* __restrict__ wQ,
    const float* __restrict__ wV,
    u16* __restrict__ pK, u16* __restrict__ pQ, u16* __restrict__ pV)
{
  int idx = blockIdx.x * 256 + threadIdx.x;   // 0..86015
  if (idx >= 86016) return;
  int set = idx / 28672;
  int r = idx - set * 28672;                  // kw*4096 + co*64 + ci
  int kw = r >> 12;
  int rem = r & 4095;
  int co = rem >> 6, ci = rem & 63;
  const float* src = set == 0 ? wK : (set == 1 ? wQ : wV);
  u16* dst = set == 0 ? pK : (set == 1 ? pQ : pV);
  dst[r] = f2bf(src[co * 448 + ci * 7 + kw]);
}

// ---------------------------------------------------------------
// Kernel 1: K and Q convs via MFMA. Block = one (b,w), 256 thr = 4 waves.
// M=64 (co, 4 tiles), N=122->128 (h', 8 tiles, 2/wave), K = kw(7) x ci(2x32)
// LDS: xt[h][ci^swz] bf16 transposed; wl[co][ci^swz] per kw.
// ---------------------------------------------------------------
__global__ __launch_bounds__(256) void conv_kq_mfma(
    const float* __restrict__ x,
    const u16* __restrict__ wpK, const u16* __restrict__ wpQ,
    const float* __restrict__ bK, const float* __restrict__ bQ,
    u16* __restrict__ qbuf, u16* __restrict__ kbuf)
{
  __shared__ u16 xt[136 * 64];
  __shared__ u16 wlK[64 * 64];
  __shared__ u16 wlQ[64 * 64];
  const int bid = blockIdx.x;
  const int b = bid >> 8, w = bid & 255;
  const int t = threadIdx.x;
  const int lane = t & 63, wv = t >> 6;

  // stage x -> xt[h][ci ^ ((h&7)<<3)], bf16, transposed (coalesced dword loads)
  {
    const float* xb = x + (size_t)b * 2097152 + (size_t)w * 128;
    #pragma unroll
    for (int it = 0; it < 8; ++it) {
      int idx = t + it * 256;
      int h = idx & 127, g = idx >> 7;     // g 0..15 -> ci quad
      int ci0 = g * 4;
      float v0 = xb[(size_t)(ci0 + 0) * 32768 + h];
      float v1 = xb[(size_t)(ci0 + 1) * 32768 + h];
      float v2 = xb[(size_t)(ci0 + 2) * 32768 + h];
      float v3 = xb[(size_t)(ci0 + 3) * 32768 + h];
      uint2 pk;
      pk.x = pack2(v0, v1);
      pk.y = pack2(v2, v3);
      int col = ci0 ^ ((h & 7) << 3);
      *reinterpret_cast<uint2*>(&xt[h * 64 + col]) = pk;
    }
    if (t < 128) {   // zero pad rows 128..135 (conv window overhang)
      int h = 128 + (t >> 4), g = t & 15;
      *reinterpret_cast<uint2*>(&xt[h * 64 + g * 4]) = make_uint2(0u, 0u);
    }
  }

  f32x4 accK[4][2], accQ[4][2];
  #pragma unroll
  for (int mt = 0; mt < 4; ++mt)
    #pragma unroll
    for (int j = 0; j < 2; ++j) {
      accK[mt][j] = (f32x4)0.f;
      accQ[mt][j] = (f32x4)0.f;
    }

  for (int kw = 0; kw < 7; ++kw) {
    __syncthreads();
    // stage both weight slices [64co][64ci] (swizzled)
    #pragma unroll
    for (int it = 0; it < 4; ++it) {
      int idx = t + it * 256;              // 0..1023 (co, ci-quad)
      int co = idx >> 4, q = idx & 15;
      int ci0 = q * 4;
      int col = ci0 ^ ((co & 7) << 3);
      uint2 dk = *reinterpret_cast<const uint2*>(wpK + ((size_t)(kw * 64 + co) * 64 + ci0));
      uint2 dq = *reinterpret_cast<const uint2*>(wpQ + ((size_t)(kw * 64 + co) * 64 + ci0));
      *reinterpret_cast<uint2*>(&wlK[co * 64 + col]) = dk;
      *reinterpret_cast<uint2*>(&wlQ[co * 64 + col]) = dq;
    }
    __syncthreads();
    #pragma unroll
    for (int ks = 0; ks < 2; ++ks) {
      int cib = ks * 32 + ((lane >> 4) << 3);
      short8 bfr[2];
      #pragma unroll
      for (int j = 0; j < 2; ++j) {
        int row = (wv * 2 + j) * 16 + (lane & 15) + kw;
        int col = cib ^ ((row & 7) << 3);
        bfr[j] = *reinterpret_cast<const short8*>(&xt[row * 64 + col]);
      }
      #pragma unroll
      for (int mt = 0; mt < 4; ++mt) {
        int co = mt * 16 + (lane & 15);
        int col = cib ^ ((co & 7) << 3);
        short8 aK = *reinterpret_cast<const short8*>(&wlK[co * 64 + col]);
        short8 aQ = *reinterpret_cast<const short8*>(&wlQ[co * 64 + col]);
        #pragma unroll
        for (int j = 0; j < 2; ++j) {
          accK[mt][j] = __builtin_amdgcn_mfma_f32_16x16x32_bf16(aK, bfr[j], accK[mt][j], 0, 0, 0);
          accQ[mt][j] = __builtin_amdgcn_mfma_f32_16x16x32_bf16(aQ, bfr[j], accQ[mt][j], 0, 0, 0);
        }
      }
    }
  }

  // store: D col = lane&15 (n), row = (lane>>4)*4 + r (co within tile)
  #pragma unroll
  for (int mt = 0; mt < 4; ++mt) {
    #pragma unroll
    for (int r = 0; r < 4; ++r) {
      int co = mt * 16 + (lane >> 4) * 4 + r;
      float bk = bK[co], bq = bQ[co];
      size_t base = ((size_t)(b * 64 + co) * 256 + w) * 122;
      #pragma unroll
      for (int j = 0; j < 2; ++j) {
        int n = (wv * 2 + j) * 16 + (lane & 15);
        if (n < 122) {
          kbuf[base + n] = f2bf(accK[mt][j][r] + bk);
          qbuf[base + n] = f2bf(accQ[mt][j][r] + bq);
        }
      }
    }
  }
}

// ---------------------------------------------------------------
// Kernel 2a: scores (Q.K^T / sqrt(d)) + masked softmax -> pbuf fp32
// ---------------------------------------------------------------
__device__ __forceinline__ float dotk(const float* qf, uint4 kv, float acc) {
  float a, b;
  up2(kv.x, a, b); acc = fmaf(qf[0], a, acc); acc = fmaf(qf[1], b, acc);
  up2(kv.y, a, b); acc = fmaf(qf[2], a, acc); acc = fmaf(qf[3], b, acc);
  up2(kv.z, a, b); acc = fmaf(qf[4], a, acc); acc = fmaf(qf[5], b, acc);
  up2(kv.w, a, b); acc = fmaf(qf[6], a, acc); acc = fmaf(qf[7], b, acc);
  return acc;
}

__global__ __launch_bounds__(512) void scores_softmax_kernel(
    const u16* __restrict__ qbuf, const u16* __restrict__ kbuf,
    float* __restrict__ pbuf)
{
  const int bid = blockIdx.x;          // b*16 + it
  const int b = bid >> 4, it = bid & 15;
  const int t = threadIdx.x;
  const int il = t >> 5, jg = t & 31;
  const int i = it * 16 + il;
  const int jbase = (it < 8) ? 128 : 0;

  const u16* qr = qbuf + (size_t)(b * 256 + i) * 7808;
  const u16* k0p = kbuf + (size_t)(b * 256 + jbase + jg * 4) * 7808;
  const u16* k1p = k0p + 7808;
  const u16* k2p = k0p + 2 * 7808;
  const u16* k3p = k0p + 3 * 7808;

  float d0 = 0.f, d1 = 0.f, d2 = 0.f, d3 = 0.f;
  for (int c = 0; c < 976; ++c) {      // 7808/8 exact
    uint4 qv = *reinterpret_cast<const uint4*>(qr + c * 8);
    float qf[8];
    up2(qv.x, qf[0], qf[1]); up2(qv.y, qf[2], qf[3]);
    up2(qv.z, qf[4], qf[5]); up2(qv.w, qf[6], qf[7]);
    uint4 k0 = *reinterpret_cast<const uint4*>(k0p + c * 8);
    uint4 k1 = *reinterpret_cast<const uint4*>(k1p + c * 8);
    uint4 k2 = *reinterpret_cast<const uint4*>(k2p + c * 8);
    uint4 k3 = *reinterpret_cast<const uint4*>(k3p + c * 8);
    d0 = dotk(qf, k0, d0); d1 = dotk(qf, k1, d1);
    d2 = dotk(qf, k2, d2); d3 = dotk(qf, k3, d3);
  }
  const float scale = 0.011316967f;    // 1/sqrt(7808)
  d0 *= scale; d1 *= scale; d2 *= scale; d3 *= scale;

  float m = fmaxf(fmaxf(d0, d1), fmaxf(d2, d3));
  #pragma unroll
  for (int off = 16; off >= 1; off >>= 1) m = fmaxf(m, __shfl_xor(m, off));
  float e0 = __expf(d0 - m), e1 = __expf(d1 - m);
  float e2 = __expf(d2 - m), e3 = __expf(d3 - m);
  float s = e0 + e1 + e2 + e3;
  #pragma unroll
  for (int off = 16; off >= 1; off >>= 1) s += __shfl_xor(s, off);
  float inv = 1.0f / s;

  float4 p4 = make_float4(e0 * inv, e1 * inv, e2 * inv, e3 * inv);
  *reinterpret_cast<float4*>(pbuf + (size_t)(b * 256 + i) * 128 + jg * 4) = p4;
}

// ---------------------------------------------------------------
// Kernel 2b: z = x + P*V (V = x raw rows), bf16 out (raw NCHW layout)
// ---------------------------------------------------------------
__global__ __launch_bounds__(256) void pv_kernel(
    const float* __restrict__ pbuf, const float* __restrict__ x,
    u16* __restrict__ zbuf)
{
  __shared__ float lp[16 * 129];
  const int bid = blockIdx.x;
  const int b = bid >> 8, r = bid & 255;
  const int it = r >> 4, ec = r & 15;
  const int t = threadIdx.x;

  for (int idx = t; idx < 2048; idx += 256) {
    int il = idx >> 7, jj = idx & 127;
    lp[il * 129 + jj] = pbuf[(size_t)(b * 256 + it * 16 + il) * 128 + jj];
  }
  __syncthreads();

  const int ig = t >> 6, eg = t & 63;
  const int jbase = (it < 8) ? 128 : 0;
  const float* vb = x + (size_t)b * 2097152 + (size_t)jbase * 8192 + ec * 512 + eg * 8;

  float acc[4][8];
  #pragma unroll
  for (int rr = 0; rr < 4; ++rr)
    #pragma unroll
    for (int e = 0; e < 8; ++e) acc[rr][e] = 0.f;

  for (int j = 0; j < 128; ++j) {
    const float* vr = vb + (size_t)j * 8192;
    float4 va = *reinterpret_cast<const float4*>(vr);
    float4 vb4 = *reinterpret_cast<const float4*>(vr + 4);
    #pragma unroll
    for (int rr = 0; rr < 4; ++rr) {
      float pj = lp[(ig * 4 + rr) * 129 + j];
      acc[rr][0] = fmaf(pj, va.x, acc[rr][0]);
      acc[rr][1] = fmaf(pj, va.y, acc[rr][1]);
      acc[rr][2] = fmaf(pj, va.z, acc[rr][2]);
      acc[rr][3] = fmaf(pj, va.w, acc[rr][3]);
      acc[rr][4] = fmaf(pj, vb4.x, acc[rr][4]);
      acc[rr][5] = fmaf(pj, vb4.y, acc[rr][5]);
      acc[rr][6] = fmaf(pj, vb4.z, acc[rr][6]);
      acc[rr][7] = fmaf(pj, vb4.w, acc[rr][7]);
    }
  }
  #pragma unroll
  for (int rr = 0; rr < 4; ++rr) {
    int i = it * 16 + ig * 4 + rr;
    size_t off = (size_t)(b * 256 + i) * 8192 + ec * 512 + eg * 8;
    const float* xr = x + (size_t)b * 2097152 + (size_t)i * 8192 + ec * 512 + eg * 8;
    float4 xa = *reinterpret_cast<const float4*>(xr);
    float4 xb4 = *reinterpret_cast<const float4*>(xr + 4);
    uint4 st;
    st.x = pack2(acc[rr][0] + xa.x, acc[rr][1] + xa.y);
    st.y = pack2(acc[rr][2] + xa.z, acc[rr][3] + xa.w);
    st.z = pack2(acc[rr][4] + xb4.x, acc[rr][5] + xb4.y);
    st.w = pack2(acc[rr][6] + xb4.z, acc[rr][7] + xb4.w);
    *reinterpret_cast<uint4*>(zbuf + off) = st;
  }
}

// ---------------------------------------------------------------
// Kernel 3: y = LeakyReLU(conv(z, wV) + bV) via MFMA, fp32 out
// ---------------------------------------------------------------
__global__ __launch_bounds__(256) void conv_out_mfma(
    const u16* __restrict__ zbuf, const u16* __restrict__ wpV,
    const float* __restrict__ bV, float* __restrict__ out)
{
  __shared__ u16 xt[136 * 64];
  __shared__ u16 wl[64 * 64];
  const int bid = blockIdx.x;
  const int b = bid >> 8, w = bid & 255;
  const int t = threadIdx.x;
  const int lane = t & 63, wv = t >> 6;

  {
    const u16* zb = zbuf + (size_t)b * 2097152 + (size_t)w * 128;
    #pragma unroll
    for (int it = 0; it < 8; ++it) {
      int idx = t + it * 256;
      int h = idx & 127, g = idx >> 7;
      int ci0 = g * 4;
      u16 v0 = zb[(size_t)(ci0 + 0) * 32768 + h];
      u16 v1 = zb[(size_t)(ci0 + 1) * 32768 + h];
      u16 v2 = zb[(size_t)(ci0 + 2) * 32768 + h];
      u16 v3 = zb[(size_t)(ci0 + 3) * 32768 + h];
      uint2 pk;
      pk.x = (uint32)v0 | ((uint32)v1 << 16);
      pk.y = (uint32)v2 | ((uint32)v3 << 16);
      int col = ci0 ^ ((h & 7) << 3);
      *reinterpret_cast<uint2*>(&xt[h * 64 + col]) = pk;
    }
    if (t < 128) {
      int h = 128 + (t >> 4), g = t & 15;
      *reinterpret_cast<uint2*>(&xt[h * 64 + g * 4]) = make_uint2(0u, 0u);
    }
  }

  f32x4 acc[4][2];
  #pragma unroll
  for (int mt = 0; mt < 4; ++mt)
    #pragma unroll
    for (int j = 0; j < 2; ++j) acc[mt][j] = (f32x4)0.f;

  for (int kw = 0; kw < 7; ++kw) {
    __syncthreads();
    #pragma unroll
    for (int it = 0; it < 4; ++it) {
      int idx = t + it * 256;
      int co = idx >> 4, q = idx & 15;
      int ci0 = q * 4;
      int col = ci0 ^ ((co & 7) << 3);
      uint2 d = *reinterpret_cast<const uint2*>(wpV + ((size_t)(kw * 64 + co) * 64 + ci0));
      *reinterpret_cast<uint2*>(&wl[co * 64 + col]) = d;
    }
    __syncthreads();
    #pragma unroll
    for (int ks = 0; ks < 2; ++ks) {
      int cib = ks * 32 + ((lane >> 4) << 3);
      short8 bfr[2];
      #pragma unroll
      for (int j = 0; j < 2; ++j) {
        int row = (wv * 2 + j) * 16 + (lane & 15) + kw;
        int col = cib ^ ((row & 7) << 3);
        bfr[j] = *reinterpret_cast<const short8*>(&xt[row * 64 + col]);
      }
      #pragma unroll
      for (int mt = 0; mt < 4; ++mt) {
        int co = mt * 16 + (lane & 15);
        int col = cib ^ ((co & 7) << 3);
        short8 aV = *reinterpret_cast<const short8*>(&wl[co * 64 + col]);
        #pragma unroll
        for (int j = 0; j < 2; ++j)
          acc[mt][j] = __builtin_amdgcn_mfma_f32_16x16x32_bf16(aV, bfr[j], acc[mt][j], 0, 0, 0);
      }
    }
  }

  #pragma unroll
  for (int mt = 0; mt < 4; ++mt) {
    #pragma unroll
    for (int r = 0; r < 4; ++r) {
      int co = mt * 16 + (lane >> 4) * 4 + r;
      float bv = bV[co];
      size_t base = ((size_t)(b * 64 + co) * 256 + w) * 122;
      #pragma unroll
      for (int j = 0; j < 2; ++j) {
        int n = (wv * 2 + j) * 16 + (lane & 15);
        if (n < 122) {
          float y = acc[mt][j][r] + bv;
          out[base + n] = (y >= 0.f) ? y : 0.2f * y;
        }
      }
    }
  }
}

// ---------------------------------------------------------------
extern "C" void kernel_launch(void* const* d_in, const int* in_sizes, int n_in,
                              void* d_out, int out_size, void* d_ws, size_t ws_size,
                              hipStream_t stream) {
  const float* x  = (const float*)d_in[0];
  const float* wK = (const float*)d_in[1];
  const float* bK = (const float*)d_in[2];
  const float* wQ = (const float*)d_in[3];
  const float* bQ = (const float*)d_in[4];
  const float* wV = (const float*)d_in[5];
  const float* bV = (const float*)d_in[6];
  float* out = (float*)d_out;

  // workspace layout (133.4 MB total):
  // [0)            zbuf bf16 67108864 B  (qbuf bf16 63963136 B aliases it:
  //                 qbuf dead after scores; zbuf written after, by pv)
  // [67108864)     kbuf bf16 63963136 B
  // [131072000)    pbuf fp32  2097152 B
  // [133169152)    wpK/wpQ/wpV bf16 57344 B each
  char* ws = (char*)d_ws;
  u16* qbuf  = (u16*)ws;
  u16* zbuf  = (u16*)ws;
  u16* kbuf  = (u16*)(ws + 67108864);
  float* pbuf = (float*)(ws + 131072000);
  u16* wpK = (u16*)(ws + 133169152);
  u16* wpQ = (u16*)(ws + 133226496);
  u16* wpV = (u16*)(ws + 133283840);

  prep_weights<<<dim3(336), dim3(256), 0, stream>>>(wK, wQ, wV, wpK, wpQ, wpV);
  conv_kq_mfma<<<dim3(16 * 256), dim3(256), 0, stream>>>(x, wpK, wpQ, bK, bQ, qbuf, kbuf);
  scores_softmax_kernel<<<dim3(16 * 16), dim3(512), 0, stream>>>(qbuf, kbuf, pbuf);
  pv_kernel<<<dim3(16 * 16 * 16), dim3(256), 0, stream>>>(pbuf, x, zbuf);
  conv_out_mfma<<<dim3(16 * 256), dim3(256), 0, stream>>>(zbuf, wpV, bV, out);
}

// Round 3
// 443.254 us; speedup vs baseline: 5.6385x; 2.8097x over previous
//
#include <hip/hip_runtime.h>
#include <hip/hip_bf16.h>

using uint32 = unsigned int;
using u16 = unsigned short;
using short8 = __attribute__((ext_vector_type(8))) short;
using f32x4  = __attribute__((ext_vector_type(4))) float;

// ---------- bf16 helpers ----------
__device__ __forceinline__ float bf2f(u16 u) {
  union { uint32 i; float f; } c; c.i = ((uint32)u) << 16; return c.f;
}
__device__ __forceinline__ u16 f2bf(float f) {
  union { float f; uint32 i; } c; c.f = f;
  uint32 u = c.i;
  u += 0x7fffu + ((u >> 16) & 1u);   // RNE
  return (u16)(u >> 16);
}
__device__ __forceinline__ uint32 pack2(float a, float b) {
  return (uint32)f2bf(a) | ((uint32)f2bf(b) << 16);
}

// Sizes: B=16, C=64, W=256, H=128, H'=122, KW=7
// k/q layout: [b][co][w][h'] contiguous == (B,256,7808) attention rows
// v = x raw: (B,256,8192); z = x + P*V in same raw layout (== NCHW image)

// ---------------------------------------------------------------
// Kernel 0: prep weights -> bf16 [kw][co][ci]
// ---------------------------------------------------------------
__global__ __launch_bounds__(256) void prep_weights(
    const float* __restrict__ wK, const float* __restrict__ wQ,
    const float* __restrict__ wV,
    u16* __restrict__ pK, u16* __restrict__ pQ, u16* __restrict__ pV)
{
  int idx = blockIdx.x * 256 + threadIdx.x;   // 0..86015
  if (idx >= 86016) return;
  int set = idx / 28672;
  int r = idx - set * 28672;                  // kw*4096 + co*64 + ci
  int kw = r >> 12;
  int rem = r & 4095;
  int co = rem >> 6, ci = rem & 63;
  const float* src = set == 0 ? wK : (set == 1 ? wQ : wV);
  u16* dst = set == 0 ? pK : (set == 1 ? pQ : pV);
  dst[r] = f2bf(src[co * 448 + ci * 7 + kw]);
}

// ---------------------------------------------------------------
// Kernel 1: K and Q convs via MFMA. Block = one (b,w), 256 thr = 4 waves.
// ---------------------------------------------------------------
__global__ __launch_bounds__(256) void conv_kq_mfma(
    const float* __restrict__ x,
    const u16* __restrict__ wpK, const u16* __restrict__ wpQ,
    const float* __restrict__ bK, const float* __restrict__ bQ,
    u16* __restrict__ qbuf, u16* __restrict__ kbuf)
{
  __shared__ u16 xt[136 * 64];
  __shared__ u16 wlK[64 * 64];
  __shared__ u16 wlQ[64 * 64];
  const int bid = blockIdx.x;
  const int b = bid >> 8, w = bid & 255;
  const int t = threadIdx.x;
  const int lane = t & 63, wv = t >> 6;

  {
    const float* xb = x + (size_t)b * 2097152 + (size_t)w * 128;
    #pragma unroll
    for (int it = 0; it < 8; ++it) {
      int idx = t + it * 256;
      int h = idx & 127, g = idx >> 7;     // g 0..15 -> ci quad
      int ci0 = g * 4;
      float v0 = xb[(size_t)(ci0 + 0) * 32768 + h];
      float v1 = xb[(size_t)(ci0 + 1) * 32768 + h];
      float v2 = xb[(size_t)(ci0 + 2) * 32768 + h];
      float v3 = xb[(size_t)(ci0 + 3) * 32768 + h];
      uint2 pk;
      pk.x = pack2(v0, v1);
      pk.y = pack2(v2, v3);
      int col = ci0 ^ ((h & 7) << 3);
      *reinterpret_cast<uint2*>(&xt[h * 64 + col]) = pk;
    }
    if (t < 128) {   // zero pad rows 128..135
      int h = 128 + (t >> 4), g = t & 15;
      *reinterpret_cast<uint2*>(&xt[h * 64 + g * 4]) = make_uint2(0u, 0u);
    }
  }

  f32x4 accK[4][2], accQ[4][2];
  #pragma unroll
  for (int mt = 0; mt < 4; ++mt)
    #pragma unroll
    for (int j = 0; j < 2; ++j) {
      accK[mt][j] = (f32x4)0.f;
      accQ[mt][j] = (f32x4)0.f;
    }

  for (int kw = 0; kw < 7; ++kw) {
    __syncthreads();
    #pragma unroll
    for (int it = 0; it < 4; ++it) {
      int idx = t + it * 256;              // 0..1023 (co, ci-quad)
      int co = idx >> 4, q = idx & 15;
      int ci0 = q * 4;
      int col = ci0 ^ ((co & 7) << 3);
      uint2 dk = *reinterpret_cast<const uint2*>(wpK + ((size_t)(kw * 64 + co) * 64 + ci0));
      uint2 dq = *reinterpret_cast<const uint2*>(wpQ + ((size_t)(kw * 64 + co) * 64 + ci0));
      *reinterpret_cast<uint2*>(&wlK[co * 64 + col]) = dk;
      *reinterpret_cast<uint2*>(&wlQ[co * 64 + col]) = dq;
    }
    __syncthreads();
    #pragma unroll
    for (int ks = 0; ks < 2; ++ks) {
      int cib = ks * 32 + ((lane >> 4) << 3);
      short8 bfr[2];
      #pragma unroll
      for (int j = 0; j < 2; ++j) {
        int row = (wv * 2 + j) * 16 + (lane & 15) + kw;
        int col = cib ^ ((row & 7) << 3);
        bfr[j] = *reinterpret_cast<const short8*>(&xt[row * 64 + col]);
      }
      #pragma unroll
      for (int mt = 0; mt < 4; ++mt) {
        int co = mt * 16 + (lane & 15);
        int col = cib ^ ((co & 7) << 3);
        short8 aK = *reinterpret_cast<const short8*>(&wlK[co * 64 + col]);
        short8 aQ = *reinterpret_cast<const short8*>(&wlQ[co * 64 + col]);
        #pragma unroll
        for (int j = 0; j < 2; ++j) {
          accK[mt][j] = __builtin_amdgcn_mfma_f32_16x16x32_bf16(aK, bfr[j], accK[mt][j], 0, 0, 0);
          accQ[mt][j] = __builtin_amdgcn_mfma_f32_16x16x32_bf16(aQ, bfr[j], accQ[mt][j], 0, 0, 0);
        }
      }
    }
  }

  #pragma unroll
  for (int mt = 0; mt < 4; ++mt) {
    #pragma unroll
    for (int r = 0; r < 4; ++r) {
      int co = mt * 16 + (lane >> 4) * 4 + r;
      float bk = bK[co], bq = bQ[co];
      size_t base = ((size_t)(b * 64 + co) * 256 + w) * 122;
      #pragma unroll
      for (int j = 0; j < 2; ++j) {
        int n = (wv * 2 + j) * 16 + (lane & 15);
        if (n < 122) {
          kbuf[base + n] = f2bf(accK[mt][j][r] + bk);
          qbuf[base + n] = f2bf(accQ[mt][j][r] + bq);
        }
      }
    }
  }
}

// ---------------------------------------------------------------
// Kernel 2a: scores via MFMA + fused masked softmax -> pbuf fp32
// grid: bid = rt*16 + b (same-b blocks share an XCD -> K-half L2 reuse)
// block: 256 thr = 4 waves; wave wq covers cols [wq*32, wq*32+32)
// A-frag = Q rows (direct global b128), B-frag = K rows (direct global b128)
// ---------------------------------------------------------------
__global__ __launch_bounds__(256) void scores_mfma(
    const u16* __restrict__ qbuf, const u16* __restrict__ kbuf,
    float* __restrict__ pbuf)
{
  __shared__ float lmax[4][16];
  __shared__ float lsum[4][16];
  const int bid = blockIdx.x;
  const int b = bid & 15, rt = bid >> 4;
  const int t = threadIdx.x;
  const int lane = t & 63, wq = t >> 6;
  const int g = lane >> 4, ln = lane & 15;
  const int i0 = rt * 16;
  const int jbase = (rt < 8) ? 128 : 0;

  const u16* qp  = qbuf + (size_t)(b * 256 + i0 + ln) * 7808 + g * 8;
  const u16* kp0 = kbuf + (size_t)(b * 256 + jbase + wq * 32 + ln) * 7808 + g * 8;
  const u16* kp1 = kp0 + (size_t)16 * 7808;

  f32x4 acc0 = (f32x4)0.f, acc1 = (f32x4)0.f;
  #pragma unroll 4
  for (int c = 0; c < 244; ++c) {
    short8 af = *reinterpret_cast<const short8*>(qp + c * 32);
    short8 b0 = *reinterpret_cast<const short8*>(kp0 + c * 32);
    short8 b1 = *reinterpret_cast<const short8*>(kp1 + c * 32);
    acc0 = __builtin_amdgcn_mfma_f32_16x16x32_bf16(af, b0, acc0, 0, 0, 0);
    acc1 = __builtin_amdgcn_mfma_f32_16x16x32_bf16(af, b1, acc1, 0, 0, 0);
  }

  const float scale = 0.011316967f;    // 1/sqrt(7808)
  float s0[4], s1[4];
  #pragma unroll
  for (int r = 0; r < 4; ++r) { s0[r] = acc0[r] * scale; s1[r] = acc1[r] * scale; }

  // intra-wave row reduce (rows live in 16-lane groups; xor<16 stays in group)
  float pm[4], ps[4];
  #pragma unroll
  for (int r = 0; r < 4; ++r) {
    float m = fmaxf(s0[r], s1[r]);
    #pragma unroll
    for (int off = 8; off >= 1; off >>= 1) m = fmaxf(m, __shfl_xor(m, off));
    float e = __expf(s0[r] - m) + __expf(s1[r] - m);
    #pragma unroll
    for (int off = 8; off >= 1; off >>= 1) e += __shfl_xor(e, off);
    pm[r] = m; ps[r] = e;
  }
  if (ln == 0) {
    #pragma unroll
    for (int r = 0; r < 4; ++r) {
      lmax[wq][g * 4 + r] = pm[r];
      lsum[wq][g * 4 + r] = ps[r];
    }
  }
  __syncthreads();

  #pragma unroll
  for (int r = 0; r < 4; ++r) {
    int row = g * 4 + r;
    float m0 = lmax[0][row], m1 = lmax[1][row], m2 = lmax[2][row], m3 = lmax[3][row];
    float mm = fmaxf(fmaxf(m0, m1), fmaxf(m2, m3));
    float ss = lsum[0][row] * __expf(m0 - mm) + lsum[1][row] * __expf(m1 - mm)
             + lsum[2][row] * __expf(m2 - mm) + lsum[3][row] * __expf(m3 - mm);
    float inv = 1.0f / ss;
    float p0 = __expf(s0[r] - mm) * inv;
    float p1 = __expf(s1[r] - mm) * inv;
    float* prow = pbuf + (size_t)(b * 256 + i0 + row) * 128 + wq * 32 + ln;
    prow[0]  = p0;
    prow[16] = p1;
  }
}

// ---------------------------------------------------------------
// Kernel 2b: z = x + P*V (V = x raw rows), bf16 out (raw NCHW layout)
// ---------------------------------------------------------------
__global__ __launch_bounds__(256) void pv_kernel(
    const float* __restrict__ pbuf, const float* __restrict__ x,
    u16* __restrict__ zbuf)
{
  __shared__ float lp[16 * 129];
  const int bid = blockIdx.x;
  const int b = bid >> 8, r = bid & 255;
  const int it = r >> 4, ec = r & 15;
  const int t = threadIdx.x;

  for (int idx = t; idx < 2048; idx += 256) {
    int il = idx >> 7, jj = idx & 127;
    lp[il * 129 + jj] = pbuf[(size_t)(b * 256 + it * 16 + il) * 128 + jj];
  }
  __syncthreads();

  const int ig = t >> 6, eg = t & 63;
  const int jbase = (it < 8) ? 128 : 0;
  const float* vb = x + (size_t)b * 2097152 + (size_t)jbase * 8192 + ec * 512 + eg * 8;

  float acc[4][8];
  #pragma unroll
  for (int rr = 0; rr < 4; ++rr)
    #pragma unroll
    for (int e = 0; e < 8; ++e) acc[rr][e] = 0.f;

  for (int j = 0; j < 128; ++j) {
    const float* vr = vb + (size_t)j * 8192;
    float4 va = *reinterpret_cast<const float4*>(vr);
    float4 vb4 = *reinterpret_cast<const float4*>(vr + 4);
    #pragma unroll
    for (int rr = 0; rr < 4; ++rr) {
      float pj = lp[(ig * 4 + rr) * 129 + j];
      acc[rr][0] = fmaf(pj, va.x, acc[rr][0]);
      acc[rr][1] = fmaf(pj, va.y, acc[rr][1]);
      acc[rr][2] = fmaf(pj, va.z, acc[rr][2]);
      acc[rr][3] = fmaf(pj, va.w, acc[rr][3]);
      acc[rr][4] = fmaf(pj, vb4.x, acc[rr][4]);
      acc[rr][5] = fmaf(pj, vb4.y, acc[rr][5]);
      acc[rr][6] = fmaf(pj, vb4.z, acc[rr][6]);
      acc[rr][7] = fmaf(pj, vb4.w, acc[rr][7]);
    }
  }
  #pragma unroll
  for (int rr = 0; rr < 4; ++rr) {
    int i = it * 16 + ig * 4 + rr;
    size_t off = (size_t)(b * 256 + i) * 8192 + ec * 512 + eg * 8;
    const float* xr = x + (size_t)b * 2097152 + (size_t)i * 8192 + ec * 512 + eg * 8;
    float4 xa = *reinterpret_cast<const float4*>(xr);
    float4 xb4 = *reinterpret_cast<const float4*>(xr + 4);
    uint4 st;
    st.x = pack2(acc[rr][0] + xa.x, acc[rr][1] + xa.y);
    st.y = pack2(acc[rr][2] + xa.z, acc[rr][3] + xa.w);
    st.z = pack2(acc[rr][4] + xb4.x, acc[rr][5] + xb4.y);
    st.w = pack2(acc[rr][6] + xb4.z, acc[rr][7] + xb4.w);
    *reinterpret_cast<uint4*>(zbuf + off) = st;
  }
}

// ---------------------------------------------------------------
// Kernel 3: y = LeakyReLU(conv(z, wV) + bV) via MFMA, fp32 out
// ---------------------------------------------------------------
__global__ __launch_bounds__(256) void conv_out_mfma(
    const u16* __restrict__ zbuf, const u16* __restrict__ wpV,
    const float* __restrict__ bV, float* __restrict__ out)
{
  __shared__ u16 xt[136 * 64];
  __shared__ u16 wl[64 * 64];
  const int bid = blockIdx.x;
  const int b = bid >> 8, w = bid & 255;
  const int t = threadIdx.x;
  const int lane = t & 63, wv = t >> 6;

  {
    const u16* zb = zbuf + (size_t)b * 2097152 + (size_t)w * 128;
    #pragma unroll
    for (int it = 0; it < 8; ++it) {
      int idx = t + it * 256;
      int h = idx & 127, g = idx >> 7;
      int ci0 = g * 4;
      u16 v0 = zb[(size_t)(ci0 + 0) * 32768 + h];
      u16 v1 = zb[(size_t)(ci0 + 1) * 32768 + h];
      u16 v2 = zb[(size_t)(ci0 + 2) * 32768 + h];
      u16 v3 = zb[(size_t)(ci0 + 3) * 32768 + h];
      uint2 pk;
      pk.x = (uint32)v0 | ((uint32)v1 << 16);
      pk.y = (uint32)v2 | ((uint32)v3 << 16);
      int col = ci0 ^ ((h & 7) << 3);
      *reinterpret_cast<uint2*>(&xt[h * 64 + col]) = pk;
    }
    if (t < 128) {
      int h = 128 + (t >> 4), g = t & 15;
      *reinterpret_cast<uint2*>(&xt[h * 64 + g * 4]) = make_uint2(0u, 0u);
    }
  }

  f32x4 acc[4][2];
  #pragma unroll
  for (int mt = 0; mt < 4; ++mt)
    #pragma unroll
    for (int j = 0; j < 2; ++j) acc[mt][j] = (f32x4)0.f;

  for (int kw = 0; kw < 7; ++kw) {
    __syncthreads();
    #pragma unroll
    for (int it = 0; it < 4; ++it) {
      int idx = t + it * 256;
      int co = idx >> 4, q = idx & 15;
      int ci0 = q * 4;
      int col = ci0 ^ ((co & 7) << 3);
      uint2 d = *reinterpret_cast<const uint2*>(wpV + ((size_t)(kw * 64 + co) * 64 + ci0));
      *reinterpret_cast<uint2*>(&wl[co * 64 + col]) = d;
    }
    __syncthreads();
    #pragma unroll
    for (int ks = 0; ks < 2; ++ks) {
      int cib = ks * 32 + ((lane >> 4) << 3);
      short8 bfr[2];
      #pragma unroll
      for (int j = 0; j < 2; ++j) {
        int row = (wv * 2 + j) * 16 + (lane & 15) + kw;
        int col = cib ^ ((row & 7) << 3);
        bfr[j] = *reinterpret_cast<const short8*>(&xt[row * 64 + col]);
      }
      #pragma unroll
      for (int mt = 0; mt < 4; ++mt) {
        int co = mt * 16 + (lane & 15);
        int col = cib ^ ((co & 7) << 3);
        short8 aV = *reinterpret_cast<const short8*>(&wl[co * 64 + col]);
        #pragma unroll
        for (int j = 0; j < 2; ++j)
          acc[mt][j] = __builtin_amdgcn_mfma_f32_16x16x32_bf16(aV, bfr[j], acc[mt][j], 0, 0, 0);
      }
    }
  }

  #pragma unroll
  for (int mt = 0; mt < 4; ++mt) {
    #pragma unroll
    for (int r = 0; r < 4; ++r) {
      int co = mt * 16 + (lane >> 4) * 4 + r;
      float bv = bV[co];
      size_t base = ((size_t)(b * 64 + co) * 256 + w) * 122;
      #pragma unroll
      for (int j = 0; j < 2; ++j) {
        int n = (wv * 2 + j) * 16 + (lane & 15);
        if (n < 122) {
          float y = acc[mt][j][r] + bv;
          out[base + n] = (y >= 0.f) ? y : 0.2f * y;
        }
      }
    }
  }
}

// ---------------------------------------------------------------
extern "C" void kernel_launch(void* const* d_in, const int* in_sizes, int n_in,
                              void* d_out, int out_size, void* d_ws, size_t ws_size,
                              hipStream_t stream) {
  const float* x  = (const float*)d_in[0];
  const float* wK = (const float*)d_in[1];
  const float* bK = (const float*)d_in[2];
  const float* wQ = (const float*)d_in[3];
  const float* bQ = (const float*)d_in[4];
  const float* wV = (const float*)d_in[5];
  const float* bV = (const float*)d_in[6];
  float* out = (float*)d_out;

  // workspace layout (133.4 MB total):
  // [0)            zbuf bf16 67108864 B  (qbuf aliases it; qbuf dead after scores)
  // [67108864)     kbuf bf16 63963136 B
  // [131072000)    pbuf fp32  2097152 B
  // [133169152)    wpK/wpQ/wpV bf16 57344 B each
  char* ws = (char*)d_ws;
  u16* qbuf  = (u16*)ws;
  u16* zbuf  = (u16*)ws;
  u16* kbuf  = (u16*)(ws + 67108864);
  float* pbuf = (float*)(ws + 131072000);
  u16* wpK = (u16*)(ws + 133169152);
  u16* wpQ = (u16*)(ws + 133226496);
  u16* wpV = (u16*)(ws + 133283840);

  prep_weights<<<dim3(336), dim3(256), 0, stream>>>(wK, wQ, wV, wpK, wpQ, wpV);
  conv_kq_mfma<<<dim3(16 * 256), dim3(256), 0, stream>>>(x, wpK, wpQ, bK, bQ, qbuf, kbuf);
  scores_mfma<<<dim3(256), dim3(256), 0, stream>>>(qbuf, kbuf, pbuf);
  pv_kernel<<<dim3(16 * 16 * 16), dim3(256), 0, stream>>>(pbuf, x, zbuf);
  conv_out_mfma<<<dim3(16 * 256), dim3(256), 0, stream>>>(zbuf, wpV, bV, out);
}

// Round 4
// 335.996 us; speedup vs baseline: 7.4384x; 1.3192x over previous
//
#include <hip/hip_runtime.h>
#include <hip/hip_bf16.h>

using uint32 = unsigned int;
using u16 = unsigned short;
using short8 = __attribute__((ext_vector_type(8))) short;
using f32x4  = __attribute__((ext_vector_type(4))) float;

// ---------- bf16 helpers ----------
__device__ __forceinline__ float bf2f(u16 u) {
  union { uint32 i; float f; } c; c.i = ((uint32)u) << 16; return c.f;
}
__device__ __forceinline__ u16 f2bf(float f) {
  union { float f; uint32 i; } c; c.f = f;
  uint32 u = c.i;
  u += 0x7fffu + ((u >> 16) & 1u);   // RNE
  return (u16)(u >> 16);
}
__device__ __forceinline__ uint32 pack2(float a, float b) {
  return (uint32)f2bf(a) | ((uint32)f2bf(b) << 16);
}

// Sizes: B=16, C=64, W=256, H=128, H'=122, KW=7
// k/q layout: [b][co][w][h'] contiguous == (B,256,7808) attention rows
// v = x raw: (B,256,8192); z = x + P*V in same raw layout (== NCHW image)

// ---------------------------------------------------------------
// Kernel 0: prep weights -> bf16 [kw][co][ci]
// ---------------------------------------------------------------
__global__ __launch_bounds__(256) void prep_weights(
    const float* __restrict__ wK, const float* __restrict__ wQ,
    const float* __restrict__ wV,
    u16* __restrict__ pK, u16* __restrict__ pQ, u16* __restrict__ pV)
{
  int idx = blockIdx.x * 256 + threadIdx.x;   // 0..86015
  if (idx >= 86016) return;
  int set = idx / 28672;
  int r = idx - set * 28672;                  // kw*4096 + co*64 + ci
  int kw = r >> 12;
  int rem = r & 4095;
  int co = rem >> 6, ci = rem & 63;
  const float* src = set == 0 ? wK : (set == 1 ? wQ : wV);
  u16* dst = set == 0 ? pK : (set == 1 ? pQ : pV);
  dst[r] = f2bf(src[co * 448 + ci * 7 + kw]);
}

// ---------------------------------------------------------------
// Kernel 1: K and Q convs via MFMA. Block = one (b,w), 256 thr = 4 waves.
// ---------------------------------------------------------------
__global__ __launch_bounds__(256) void conv_kq_mfma(
    const float* __restrict__ x,
    const u16* __restrict__ wpK, const u16* __restrict__ wpQ,
    const float* __restrict__ bK, const float* __restrict__ bQ,
    u16* __restrict__ qbuf, u16* __restrict__ kbuf)
{
  __shared__ u16 xt[136 * 64];
  __shared__ u16 wlK[64 * 64];
  __shared__ u16 wlQ[64 * 64];
  const int bid = blockIdx.x;
  const int b = bid >> 8, w = bid & 255;
  const int t = threadIdx.x;
  const int lane = t & 63, wv = t >> 6;

  {
    const float* xb = x + (size_t)b * 2097152 + (size_t)w * 128;
    #pragma unroll
    for (int it = 0; it < 8; ++it) {
      int idx = t + it * 256;
      int h = idx & 127, g = idx >> 7;     // g 0..15 -> ci quad
      int ci0 = g * 4;
      float v0 = xb[(size_t)(ci0 + 0) * 32768 + h];
      float v1 = xb[(size_t)(ci0 + 1) * 32768 + h];
      float v2 = xb[(size_t)(ci0 + 2) * 32768 + h];
      float v3 = xb[(size_t)(ci0 + 3) * 32768 + h];
      uint2 pk;
      pk.x = pack2(v0, v1);
      pk.y = pack2(v2, v3);
      int col = ci0 ^ ((h & 7) << 3);
      *reinterpret_cast<uint2*>(&xt[h * 64 + col]) = pk;
    }
    if (t < 128) {   // zero pad rows 128..135
      int h = 128 + (t >> 4), g = t & 15;
      *reinterpret_cast<uint2*>(&xt[h * 64 + g * 4]) = make_uint2(0u, 0u);
    }
  }

  f32x4 accK[4][2], accQ[4][2];
  #pragma unroll
  for (int mt = 0; mt < 4; ++mt)
    #pragma unroll
    for (int j = 0; j < 2; ++j) {
      accK[mt][j] = (f32x4)0.f;
      accQ[mt][j] = (f32x4)0.f;
    }

  for (int kw = 0; kw < 7; ++kw) {
    __syncthreads();
    #pragma unroll
    for (int it = 0; it < 4; ++it) {
      int idx = t + it * 256;              // 0..1023 (co, ci-quad)
      int co = idx >> 4, q = idx & 15;
      int ci0 = q * 4;
      int col = ci0 ^ ((co & 7) << 3);
      uint2 dk = *reinterpret_cast<const uint2*>(wpK + ((size_t)(kw * 64 + co) * 64 + ci0));
      uint2 dq = *reinterpret_cast<const uint2*>(wpQ + ((size_t)(kw * 64 + co) * 64 + ci0));
      *reinterpret_cast<uint2*>(&wlK[co * 64 + col]) = dk;
      *reinterpret_cast<uint2*>(&wlQ[co * 64 + col]) = dq;
    }
    __syncthreads();
    #pragma unroll
    for (int ks = 0; ks < 2; ++ks) {
      int cib = ks * 32 + ((lane >> 4) << 3);
      short8 bfr[2];
      #pragma unroll
      for (int j = 0; j < 2; ++j) {
        int row = (wv * 2 + j) * 16 + (lane & 15) + kw;
        int col = cib ^ ((row & 7) << 3);
        bfr[j] = *reinterpret_cast<const short8*>(&xt[row * 64 + col]);
      }
      #pragma unroll
      for (int mt = 0; mt < 4; ++mt) {
        int co = mt * 16 + (lane & 15);
        int col = cib ^ ((co & 7) << 3);
        short8 aK = *reinterpret_cast<const short8*>(&wlK[co * 64 + col]);
        short8 aQ = *reinterpret_cast<const short8*>(&wlQ[co * 64 + col]);
        #pragma unroll
        for (int j = 0; j < 2; ++j) {
          accK[mt][j] = __builtin_amdgcn_mfma_f32_16x16x32_bf16(aK, bfr[j], accK[mt][j], 0, 0, 0);
          accQ[mt][j] = __builtin_amdgcn_mfma_f32_16x16x32_bf16(aQ, bfr[j], accQ[mt][j], 0, 0, 0);
        }
      }
    }
  }

  #pragma unroll
  for (int mt = 0; mt < 4; ++mt) {
    #pragma unroll
    for (int r = 0; r < 4; ++r) {
      int co = mt * 16 + (lane >> 4) * 4 + r;
      float bk = bK[co], bq = bQ[co];
      size_t base = ((size_t)(b * 64 + co) * 256 + w) * 122;
      #pragma unroll
      for (int j = 0; j < 2; ++j) {
        int n = (wv * 2 + j) * 16 + (lane & 15);
        if (n < 122) {
          kbuf[base + n] = f2bf(accK[mt][j][r] + bk);
          qbuf[base + n] = f2bf(accQ[mt][j][r] + bq);
        }
      }
    }
  }
}

// ---------------------------------------------------------------
// Kernel 2a: scores via MFMA + fused masked softmax -> pbuf fp32
// ---------------------------------------------------------------
__global__ __launch_bounds__(256) void scores_mfma(
    const u16* __restrict__ qbuf, const u16* __restrict__ kbuf,
    float* __restrict__ pbuf)
{
  __shared__ float lmax[4][16];
  __shared__ float lsum[4][16];
  const int bid = blockIdx.x;
  const int b = bid & 15, rt = bid >> 4;
  const int t = threadIdx.x;
  const int lane = t & 63, wq = t >> 6;
  const int g = lane >> 4, ln = lane & 15;
  const int i0 = rt * 16;
  const int jbase = (rt < 8) ? 128 : 0;

  const u16* qp  = qbuf + (size_t)(b * 256 + i0 + ln) * 7808 + g * 8;
  const u16* kp0 = kbuf + (size_t)(b * 256 + jbase + wq * 32 + ln) * 7808 + g * 8;
  const u16* kp1 = kp0 + (size_t)16 * 7808;

  f32x4 acc0 = (f32x4)0.f, acc1 = (f32x4)0.f;
  #pragma unroll 4
  for (int c = 0; c < 244; ++c) {
    short8 af = *reinterpret_cast<const short8*>(qp + c * 32);
    short8 b0 = *reinterpret_cast<const short8*>(kp0 + c * 32);
    short8 b1 = *reinterpret_cast<const short8*>(kp1 + c * 32);
    acc0 = __builtin_amdgcn_mfma_f32_16x16x32_bf16(af, b0, acc0, 0, 0, 0);
    acc1 = __builtin_amdgcn_mfma_f32_16x16x32_bf16(af, b1, acc1, 0, 0, 0);
  }

  const float scale = 0.011316967f;    // 1/sqrt(7808)
  float s0[4], s1[4];
  #pragma unroll
  for (int r = 0; r < 4; ++r) { s0[r] = acc0[r] * scale; s1[r] = acc1[r] * scale; }

  float pm[4], ps[4];
  #pragma unroll
  for (int r = 0; r < 4; ++r) {
    float m = fmaxf(s0[r], s1[r]);
    #pragma unroll
    for (int off = 8; off >= 1; off >>= 1) m = fmaxf(m, __shfl_xor(m, off));
    float e = __expf(s0[r] - m) + __expf(s1[r] - m);
    #pragma unroll
    for (int off = 8; off >= 1; off >>= 1) e += __shfl_xor(e, off);
    pm[r] = m; ps[r] = e;
  }
  if (ln == 0) {
    #pragma unroll
    for (int r = 0; r < 4; ++r) {
      lmax[wq][g * 4 + r] = pm[r];
      lsum[wq][g * 4 + r] = ps[r];
    }
  }
  __syncthreads();

  #pragma unroll
  for (int r = 0; r < 4; ++r) {
    int row = g * 4 + r;
    float m0 = lmax[0][row], m1 = lmax[1][row], m2 = lmax[2][row], m3 = lmax[3][row];
    float mm = fmaxf(fmaxf(m0, m1), fmaxf(m2, m3));
    float ss = lsum[0][row] * __expf(m0 - mm) + lsum[1][row] * __expf(m1 - mm)
             + lsum[2][row] * __expf(m2 - mm) + lsum[3][row] * __expf(m3 - mm);
    float inv = 1.0f / ss;
    float p0 = __expf(s0[r] - mm) * inv;
    float p1 = __expf(s1[r] - mm) * inv;
    float* prow = pbuf + (size_t)(b * 256 + i0 + row) * 128 + wq * 32 + ln;
    prow[0]  = p0;
    prow[16] = p1;
  }
}

// ---------------------------------------------------------------
// Kernel 2b: z = x + P*V via MFMA, bf16 out (raw NCHW layout)
// Block = (b, half hb, e-chunk 256). 4 waves split M=128 (rows of one half).
// A = P (bf16, LDS pl[128][136] padded), B = V^T staged per 32-k step into
// vt[e][j] with 80B row stride (16B-aligned b128 frags, 8-bank/2-way free).
// K = 128 (the unmasked half), fp32 accum; epilogue fuses z = x + PV.
// ---------------------------------------------------------------
__global__ __launch_bounds__(256) void pv_mfma(
    const float* __restrict__ pbuf, const float* __restrict__ x,
    u16* __restrict__ zbuf)
{
  __shared__ u16 pl[128 * 136];   // 34816 B
  __shared__ u16 vt[256 * 40];    // 20480 B
  const int bid = blockIdx.x;
  const int b  = bid >> 6;
  const int hb = (bid >> 5) & 1;
  const int ec = bid & 31;
  const int t = threadIdx.x;
  const int lane = t & 63, wv = t >> 6;
  const int ln = lane & 15, g = lane >> 4;

  const int i0 = hb ? 0 : 128;        // output rows
  const int jbase = hb ? 128 : 0;     // V rows (opposite half)
  const int e0 = ec * 256;
  const float* xb = x + (size_t)b * 2097152;
  const float* pb = pbuf + (size_t)(b * 256 + i0) * 128;

  // stage P[128][128] fp32 -> bf16 pl (row stride 136 u16 = 272 B)
  uint32* plw = reinterpret_cast<uint32*>(pl);
  #pragma unroll
  for (int it = 0; it < 32; ++it) {
    int idx = t + it * 256;           // 0..8191 u32 units
    int ii = idx >> 6, jjp = idx & 63;
    float2 f2 = *reinterpret_cast<const float2*>(pb + ii * 128 + jjp * 2);
    plw[ii * 68 + jjp] = pack2(f2.x, f2.y);
  }

  f32x4 acc[2][16];
  #pragma unroll
  for (int mt = 0; mt < 2; ++mt)
    #pragma unroll
    for (int nt = 0; nt < 16; ++nt) acc[mt][nt] = (f32x4)0.f;

  uint32* vtw = reinterpret_cast<uint32*>(vt);
  for (int ks = 0; ks < 4; ++ks) {
    __syncthreads();
    // stage V k-step: rows jbase+ks*32..+32, cols e0..e0+256, transposed
    #pragma unroll
    for (int it = 0; it < 16; ++it) {
      int idx = t + it * 256;         // 0..4095
      int e = idx & 255, jp = idx >> 8;   // jp 0..15 (j-pair)
      const float* vr = xb + (size_t)(jbase + ks * 32 + jp * 2) * 8192 + e0 + e;
      float f0 = vr[0];
      float f1 = vr[8192];
      vtw[e * 20 + jp] = pack2(f0, f1);
    }
    __syncthreads();
    short8 af[2];
    #pragma unroll
    for (int mt = 0; mt < 2; ++mt) {
      int row = wv * 32 + mt * 16 + ln;
      af[mt] = *reinterpret_cast<const short8*>(&pl[row * 136 + ks * 32 + g * 8]);
    }
    #pragma unroll
    for (int nt = 0; nt < 16; ++nt) {
      int e = nt * 16 + ln;
      short8 bf = *reinterpret_cast<const short8*>(&vt[e * 40 + g * 8]);
      acc[0][nt] = __builtin_amdgcn_mfma_f32_16x16x32_bf16(af[0], bf, acc[0][nt], 0, 0, 0);
      acc[1][nt] = __builtin_amdgcn_mfma_f32_16x16x32_bf16(af[1], bf, acc[1][nt], 0, 0, 0);
    }
  }

  // epilogue: z = x + acc -> bf16 (D: col = ln -> e, row = g*4+r)
  #pragma unroll
  for (int mt = 0; mt < 2; ++mt) {
    #pragma unroll
    for (int r = 0; r < 4; ++r) {
      int i = i0 + wv * 32 + mt * 16 + g * 4 + r;
      const float* xr = xb + (size_t)i * 8192 + e0 + ln;
      u16* zr = zbuf + (size_t)(b * 256 + i) * 8192 + e0 + ln;
      #pragma unroll
      for (int nt = 0; nt < 16; ++nt) {
        float z = xr[nt * 16] + acc[mt][nt][r];
        zr[nt * 16] = f2bf(z);
      }
    }
  }
}

// ---------------------------------------------------------------
// Kernel 3: y = LeakyReLU(conv(z, wV) + bV) via MFMA, fp32 out
// ---------------------------------------------------------------
__global__ __launch_bounds__(256) void conv_out_mfma(
    const u16* __restrict__ zbuf, const u16* __restrict__ wpV,
    const float* __restrict__ bV, float* __restrict__ out)
{
  __shared__ u16 xt[136 * 64];
  __shared__ u16 wl[64 * 64];
  const int bid = blockIdx.x;
  const int b = bid >> 8, w = bid & 255;
  const int t = threadIdx.x;
  const int lane = t & 63, wv = t >> 6;

  {
    const u16* zb = zbuf + (size_t)b * 2097152 + (size_t)w * 128;
    #pragma unroll
    for (int it = 0; it < 8; ++it) {
      int idx = t + it * 256;
      int h = idx & 127, g = idx >> 7;
      int ci0 = g * 4;
      u16 v0 = zb[(size_t)(ci0 + 0) * 32768 + h];
      u16 v1 = zb[(size_t)(ci0 + 1) * 32768 + h];
      u16 v2 = zb[(size_t)(ci0 + 2) * 32768 + h];
      u16 v3 = zb[(size_t)(ci0 + 3) * 32768 + h];
      uint2 pk;
      pk.x = (uint32)v0 | ((uint32)v1 << 16);
      pk.y = (uint32)v2 | ((uint32)v3 << 16);
      int col = ci0 ^ ((h & 7) << 3);
      *reinterpret_cast<uint2*>(&xt[h * 64 + col]) = pk;
    }
    if (t < 128) {
      int h = 128 + (t >> 4), g = t & 15;
      *reinterpret_cast<uint2*>(&xt[h * 64 + g * 4]) = make_uint2(0u, 0u);
    }
  }

  f32x4 acc[4][2];
  #pragma unroll
  for (int mt = 0; mt < 4; ++mt)
    #pragma unroll
    for (int j = 0; j < 2; ++j) acc[mt][j] = (f32x4)0.f;

  for (int kw = 0; kw < 7; ++kw) {
    __syncthreads();
    #pragma unroll
    for (int it = 0; it < 4; ++it) {
      int idx = t + it * 256;
      int co = idx >> 4, q = idx & 15;
      int ci0 = q * 4;
      int col = ci0 ^ ((co & 7) << 3);
      uint2 d = *reinterpret_cast<const uint2*>(wpV + ((size_t)(kw * 64 + co) * 64 + ci0));
      *reinterpret_cast<uint2*>(&wl[co * 64 + col]) = d;
    }
    __syncthreads();
    #pragma unroll
    for (int ks = 0; ks < 2; ++ks) {
      int cib = ks * 32 + ((lane >> 4) << 3);
      short8 bfr[2];
      #pragma unroll
      for (int j = 0; j < 2; ++j) {
        int row = (wv * 2 + j) * 16 + (lane & 15) + kw;
        int col = cib ^ ((row & 7) << 3);
        bfr[j] = *reinterpret_cast<const short8*>(&xt[row * 64 + col]);
      }
      #pragma unroll
      for (int mt = 0; mt < 4; ++mt) {
        int co = mt * 16 + (lane & 15);
        int col = cib ^ ((co & 7) << 3);
        short8 aV = *reinterpret_cast<const short8*>(&wl[co * 64 + col]);
        #pragma unroll
        for (int j = 0; j < 2; ++j)
          acc[mt][j] = __builtin_amdgcn_mfma_f32_16x16x32_bf16(aV, bfr[j], acc[mt][j], 0, 0, 0);
      }
    }
  }

  #pragma unroll
  for (int mt = 0; mt < 4; ++mt) {
    #pragma unroll
    for (int r = 0; r < 4; ++r) {
      int co = mt * 16 + (lane >> 4) * 4 + r;
      float bv = bV[co];
      size_t base = ((size_t)(b * 64 + co) * 256 + w) * 122;
      #pragma unroll
      for (int j = 0; j < 2; ++j) {
        int n = (wv * 2 + j) * 16 + (lane & 15);
        if (n < 122) {
          float y = acc[mt][j][r] + bv;
          out[base + n] = (y >= 0.f) ? y : 0.2f * y;
        }
      }
    }
  }
}

// ---------------------------------------------------------------
extern "C" void kernel_launch(void* const* d_in, const int* in_sizes, int n_in,
                              void* d_out, int out_size, void* d_ws, size_t ws_size,
                              hipStream_t stream) {
  const float* x  = (const float*)d_in[0];
  const float* wK = (const float*)d_in[1];
  const float* bK = (const float*)d_in[2];
  const float* wQ = (const float*)d_in[3];
  const float* bQ = (const float*)d_in[4];
  const float* wV = (const float*)d_in[5];
  const float* bV = (const float*)d_in[6];
  float* out = (float*)d_out;

  // workspace layout (133.4 MB total):
  // [0)            zbuf bf16 67108864 B  (qbuf aliases it; qbuf dead after scores)
  // [67108864)     kbuf bf16 63963136 B
  // [131072000)    pbuf fp32  2097152 B
  // [133169152)    wpK/wpQ/wpV bf16 57344 B each
  char* ws = (char*)d_ws;
  u16* qbuf  = (u16*)ws;
  u16* zbuf  = (u16*)ws;
  u16* kbuf  = (u16*)(ws + 67108864);
  float* pbuf = (float*)(ws + 131072000);
  u16* wpK = (u16*)(ws + 133169152);
  u16* wpQ = (u16*)(ws + 133226496);
  u16* wpV = (u16*)(ws + 133283840);

  prep_weights<<<dim3(336), dim3(256), 0, stream>>>(wK, wQ, wV, wpK, wpQ, wpV);
  conv_kq_mfma<<<dim3(16 * 256), dim3(256), 0, stream>>>(x, wpK, wpQ, bK, bQ, qbuf, kbuf);
  scores_mfma<<<dim3(256), dim3(256), 0, stream>>>(qbuf, kbuf, pbuf);
  pv_mfma<<<dim3(1024), dim3(256), 0, stream>>>(pbuf, x, zbuf);
  conv_out_mfma<<<dim3(16 * 256), dim3(256), 0, stream>>>(zbuf, wpV, bV, out);
}